// Round 6
// baseline (453.124 us; speedup 1.0000x reference)
//
#include <hip/hip_runtime.h>
#include <hip/hip_bf16.h>

// 4-D "same" conv as implicit GEMM on bf16 MFMA.
// R6: LDS-STAGED B-operand. R5 post-mortem: VGPR=36 proved the compiler
//   collapsed the dbuf; arithmetic shows 3.48 GB of B-gathers / 135 us =
//   25.7 TB/s ~ 75% of L2 peak -> L2-BW-bound (L1 thrashes: 7 blocks/CU x
//   60 KB disjoint working set vs 32 KB L1). Fix: route the forced B-bytes
//   through LDS (85-112 B/cyc/CU vs ~42 measured via L1/L2).
//   Block = (g, p1, p2, 8x8 (p3,p4) patch): stage (3,3,10,10)xCIN halo
//   region for 4 batches (57.6 KB) once, compute 21 chunks from LDS.
//   Wave = one 4x4 (p3,p4) tile, NB=4 batches. 79.5 KB LDS -> 2 blocks/CU.
// Also: clamp K-pad taps 81-83 to offset 0 (A-frag is zero; fixes latent
//   OOB gather past xTp present in R3/R5).
// Paths: LDS-MFMA (ws >= 58.5 MB) -> old unpadded-MFMA (ws >= 42.5 MB)
//        -> direct fp32 (insurance).

#define SDIM  24
#define SP    (SDIM * SDIM * SDIM * SDIM)   // 331776
#define PD    26
#define SPPAD (PD * PD * PD * PD)            // 456976
#define CIN   8
#define COUT  16
#define BATCH 8
#define KW    648                            // 81 * CIN
#define NCHUNK 21                            // ceil(648/32)
#define NB    4                              // batches per wave
#define PTILES (SP / 16)                     // 20736 (fallback path)
#define NBLOCKS_OLD ((BATCH / NB) * PTILES / 4)

// new-block grid: 2 g-groups x 24 p1 x 24 p2 x 3 S3 x 3 S4
#define NBLK  (2 * 24 * 24 * 3 * 3)          // 10368

#define ZERO_OFF 0
#define WPK_OFF  256
#define XT_OFF   32768
#define XT_BYTES  ((size_t)BATCH * SP * CIN * 2)          // 42,467,328
#define XTP_BYTES ((size_t)BATCH * SPPAD * CIN * 2)       // 58,492,928
#define WS_NEEDED_OLD (XT_OFF + XT_BYTES)
#define WS_NEEDED_PAD (XT_OFF + XTP_BYTES)

// ---- halo shell enumeration (per batch): SPPAD - SP = 125,200 slots ----
#define HALO_PER_B   125200
#define HROW_SLOTS   97552
#define HALO_TOTAL   (BATCH * HALO_PER_B)    // 1,001,600
#define HBLOCKS      3913                    // ceil(HALO_TOTAL/256)
#define TBLOCKS      (BATCH * SP / 4 / 256)  // 2592 transpose blocks
#define WBLOCKS      6                       // weight-pack blocks
#define PREP_BLOCKS  (HBLOCKS + TBLOCKS + WBLOCKS)

typedef __attribute__((ext_vector_type(8))) short short8;   // 8 bf16 = 4 VGPRs
typedef __attribute__((ext_vector_type(4))) float f32x4;

static __device__ __forceinline__ unsigned short f2bf(float f) {
    unsigned u = __builtin_bit_cast(unsigned, f);
    u = (u + 0x7fffu + ((u >> 16) & 1u)) >> 16;          // RNE
    return (unsigned short)u;
}

// ---------- fused prepass: halo-zero + transpose + weights ----------
__global__ __launch_bounds__(256) void prep_fused(
    const float* __restrict__ x, const float* __restrict__ w,
    unsigned char* __restrict__ ws)
{
    const int bid = blockIdx.x;
    const int tid = threadIdx.x;

    if (bid < HBLOCKS) {
        // ---- halo-only zero fill ----
        int t = bid * 256 + tid;
        if (t >= HALO_TOTAL) return;
        int b = t / HALO_PER_B;
        int h = t - b * HALO_PER_B;
        int q1, q2, q3, q4;
        if (h < HROW_SLOTS) {
            int rid = h / 26;
            q4 = h - rid * 26;
            if (rid < 1352) {                            // q1 in {0,25}
                q1 = (rid < 676) ? 0 : 25;
                int rr = rid % 676;
                q2 = rr / 26; q3 = rr - (rr / 26) * 26;
            } else if (rid < 2600) {                     // q1 in [1,24], q2 in {0,25}
                int r2 = rid - 1352;
                q1 = 1 + r2 / 52;
                int rr = r2 - (r2 / 52) * 52;
                q2 = (rr < 26) ? 0 : 25;
                q3 = rr % 26;
            } else {                                     // q1,q2 in [1,24], q3 in {0,25}
                int r3 = rid - 2600;
                q1 = 1 + r3 / 48;
                int rr = r3 - (r3 / 48) * 48;
                q2 = 1 + rr / 2;
                q3 = (rr & 1) ? 25 : 0;
            }
        } else {
            int e = h - HROW_SLOTS;                      // [0, 27648)
            int rid = e >> 1;
            q4 = (e & 1) ? 25 : 0;
            q1 = 1 + rid / 576;
            int rr = rid - (rid / 576) * 576;
            q2 = 1 + rr / 24;
            q3 = 1 + rr - (rr / 24) * 24;
        }
        size_t slot = (size_t)b * SPPAD + (((q1 * PD + q2) * PD + q3) * PD + q4);
        short8 z = {0, 0, 0, 0, 0, 0, 0, 0};
        ((short8*)(ws + XT_OFF))[slot] = z;
        return;
    }

    if (bid < HBLOCKS + TBLOCKS) {
        // ---- transpose: x (B,CIN,SP) fp32 -> xTp interior (B,26^4,CIN) bf16 ----
        int idx = (bid - HBLOCKS) * 256 + tid;
        int b  = idx / (SP / 4);
        int pq = idx - b * (SP / 4);
        int p  = pq * 4;
        const float* xb = x + (size_t)b * CIN * SP + p;

        float4 v[CIN];
        #pragma unroll
        for (int c = 0; c < CIN; ++c)
            v[c] = *(const float4*)(xb + (size_t)c * SP);

        union { __hip_bfloat162 h2[4]; short8 s8; } u[4];
        #pragma unroll
        for (int j = 0; j < 4; ++j) {
            #pragma unroll
            for (int i = 0; i < 4; ++i) {
                float a0 = (&v[2 * i].x)[j];
                float a1 = (&v[2 * i + 1].x)[j];
                u[j].h2[i] = __float22bfloat162_rn(make_float2(a0, a1));
            }
        }

        int r = p;
        const int p4 = r % SDIM; r /= SDIM;
        const int p3 = r % SDIM; r /= SDIM;
        const int p2 = r % SDIM;
        const int p1 = r / SDIM;
        int qp = (((p1 + 1) * PD + (p2 + 1)) * PD + (p3 + 1)) * PD + (p4 + 1);

        short8* dst = (short8*)(ws + XT_OFF) + (size_t)b * SPPAD + qp;
        #pragma unroll
        for (int j = 0; j < 4; ++j) dst[j] = u[j].s8;
        return;
    }

    // ---- weight pack -> A-frag order Wpack[chunk][lane][8] bf16 ----
    int t = (bid - HBLOCKS - TBLOCKS) * 256 + tid;
    if (t >= NCHUNK * 64) return;
    int chunk = t >> 6;
    int lane  = t & 63;
    int m     = lane & 15;
    int quad  = lane >> 4;
    short8 pk;
    #pragma unroll
    for (int j = 0; j < 8; ++j) {
        int k = chunk * 32 + quad * 8 + j;
        float f = (k < KW) ? w[m * KW + k] : 0.0f;
        pk[j] = (short)f2bf(f);
    }
    ((short8*)(ws + WPK_OFF))[chunk * 64 + lane] = pk;
}

// ---------- main: LDS-staged implicit GEMM ----------
// block: (g, p1, p2, S3, S4); stages x region (3,3,10,10)xCIN for 4 batches.
// wave (wt3,wt4) = one 4x4 (p3,p4) tile; lane col -> (c3,c4) = (col>>2, col&3).
__global__ __launch_bounds__(256, 2) void conv4d_lds(
    const unsigned char* __restrict__ ws,
    const float* __restrict__ bias,
    float* __restrict__ out)
{
    __shared__ short8 s_x[4 * 900];           // 57600 B [batch][d1][d2][r3][r4]
    __shared__ short8 s_w[NCHUNK * 64];       // 21504 B weight pack
    __shared__ int    s_dly[96];              // staged-coord tap deltas (short8 units)

    const int tid  = threadIdx.x;
    const int lane = tid & 63;
    const int wave = tid >> 6;
    const int col  = lane & 15;
    const int quad = lane >> 4;
    const int c3   = col >> 2;
    const int c4   = col & 3;
    const int wt3  = wave >> 1;
    const int wt4  = wave & 1;

    // block coords
    int bid = __builtin_amdgcn_readfirstlane((int)blockIdx.x);
    const int g  = bid / 5184;  int r = bid - g * 5184;
    const int p1 = r / 216;     r -= p1 * 216;
    const int p2 = r / 9;       int s = r - p2 * 9;
    const int S3 = (s / 3) * 8;
    const int S4 = (s % 3) * 8;

    // LDS fills
    const short8* wpk = (const short8*)(ws + WPK_OFF);
    for (int t = tid; t < NCHUNK * 64; t += 256) s_w[t] = wpk[t];
    if (tid < 84) {
        if (tid >= 81) {                       // K-pad taps: A-frag is zero; safe idx
            s_dly[tid] = 0;
        } else {
            int k1 = tid / 27, rem = tid - k1 * 27;
            int k2 = rem / 9;  rem -= k2 * 9;
            int k3 = rem / 3;
            int k4 = rem - k3 * 3;
            s_dly[tid] = ((k1 * 3 + k2) * 10 + k3) * 10 + k4;
        }
    }

    // stage x region: padded coords q1 = p1+d1 (d1 0..2), q3 = S3+r3 (r3 0..9), ...
    const short8* xT = (const short8*)(ws + XT_OFF);
    for (int t = tid; t < 3600; t += 256) {
        int b  = t / 900;
        int rr = t - b * 900;
        int d1 = rr / 300;  rr -= d1 * 300;
        int d2 = rr / 100;  rr -= d2 * 100;
        int r3 = rr / 10;
        int r4 = rr - r3 * 10;
        size_t gq = (((size_t)(p1 + d1) * PD + (p2 + d2)) * PD + (S3 + r3)) * PD + (S4 + r4);
        s_x[t] = xT[(size_t)(g * NB + b) * SPPAD + gq];
    }
    __syncthreads();

    const int lane_off = (wt3 * 4 + c3) * 10 + (wt4 * 4 + c4);

    f32x4 acc[NB];
    #pragma unroll
    for (int t = 0; t < NB; ++t) acc[t] = (f32x4){0.f, 0.f, 0.f, 0.f};

    #pragma unroll
    for (int c = 0; c < NCHUNK; ++c) {
        short8 afrag = s_w[c * 64 + lane];               // ds_read_b128
        int bidx = s_dly[c * 4 + quad] + lane_off;       // ds_read_b32 (quad-bcast)

        short8 bf[NB];
        #pragma unroll
        for (int t = 0; t < NB; ++t)
            bf[t] = s_x[t * 900 + bidx];                 // ds_read_b128
        #pragma unroll
        for (int t = 0; t < NB; ++t)
            acc[t] = __builtin_amdgcn_mfma_f32_16x16x32_bf16(afrag, bf[t], acc[t], 0, 0, 0);
    }

    // epilogue: D[row=quad*4+reg][col] -> out[b][row][p1,p2,p3,p4] ; add bias
    const int p3 = S3 + wt3 * 4 + c3;
    const int p4 = S4 + wt4 * 4 + c4;
    const size_t pos = (((size_t)p1 * SDIM + p2) * SDIM + p3) * SDIM + p4;
    f32x4 b4 = *(const f32x4*)(bias + quad * 4);
    #pragma unroll
    for (int t = 0; t < NB; ++t) {
        float* obase = out + ((size_t)(g * NB + t) * COUT + quad * 4) * SP + pos;
        #pragma unroll
        for (int reg = 0; reg < 4; ++reg)
            obase[(size_t)reg * SP] = acc[t][reg] + b4[reg];
    }
}

// ================= old (unpadded) path — middle fallback =================

__global__ __launch_bounds__(256) void pack_weights(
    const float* __restrict__ w, unsigned char* __restrict__ ws)
{
    int t = blockIdx.x * 256 + threadIdx.x;
    if (t == 1344) {
        short8 z = {0,0,0,0,0,0,0,0};
        *(short8*)(ws + ZERO_OFF) = z;
    }
    if (t >= NCHUNK * 64) return;
    int chunk = t >> 6;
    int lane  = t & 63;
    int m     = lane & 15;
    int quad  = lane >> 4;
    short8 pk;
    #pragma unroll
    for (int j = 0; j < 8; ++j) {
        int k = chunk * 32 + quad * 8 + j;
        float f = (k < KW) ? w[m * KW + k] : 0.0f;
        pk[j] = (short)f2bf(f);
    }
    ((short8*)(ws + WPK_OFF))[chunk * 64 + lane] = pk;
}

__global__ __launch_bounds__(256) void transpose_x(
    const float* __restrict__ x, unsigned char* __restrict__ ws)
{
    int idx = blockIdx.x * 256 + threadIdx.x;
    int b  = idx / (SP / 2);
    int pp = idx - b * (SP / 2);
    int p  = pp * 2;
    const float* xb = x + (size_t)b * CIN * SP + p;

    float2 v[CIN];
    #pragma unroll
    for (int c = 0; c < CIN; ++c)
        v[c] = *(const float2*)(xb + (size_t)c * SP);

    union { __hip_bfloat162 h2[4]; short8 s8; } u0, u1;
    #pragma unroll
    for (int i = 0; i < 4; ++i) {
        float2 a = make_float2(v[2 * i].x, v[2 * i + 1].x);
        float2 bq = make_float2(v[2 * i].y, v[2 * i + 1].y);
        u0.h2[i] = __float22bfloat162_rn(a);
        u1.h2[i] = __float22bfloat162_rn(bq);
    }
    short8* dst = (short8*)(ws + XT_OFF) + ((size_t)b * SP + p);
    dst[0] = u0.s8;
    dst[1] = u1.s8;
}

__global__ __launch_bounds__(256) void conv4d_mfma(
    const unsigned char* __restrict__ ws,
    const float* __restrict__ bias,
    float* __restrict__ out)
{
    const int lane = threadIdx.x & 63;
    const int wave = threadIdx.x >> 6;
    const int col  = lane & 15;
    const int quad = lane >> 4;

    int W = blockIdx.x * 4 + wave;
    W = __builtin_amdgcn_readfirstlane(W);
    const int pt = W % PTILES;
    const int g  = W / PTILES;

    const int p = pt * 16 + col;
    int r = p;
    const int p4 = r % SDIM; r /= SDIM;
    const int p3 = r % SDIM; r /= SDIM;
    const int p2 = r % SDIM;
    const int p1 = r / SDIM;

    const short8* wpk  = (const short8*)(ws + WPK_OFF);
    const short8* xT   = (const short8*)(ws + XT_OFF);
    const short8* zslt = (const short8*)(ws + ZERO_OFF);

    const short8* xb[NB];
    #pragma unroll
    for (int t = 0; t < NB; ++t)
        xb[t] = xT + (size_t)(g * NB + t) * SP;

    f32x4 acc[NB];
    #pragma unroll
    for (int t = 0; t < NB; ++t) acc[t] = (f32x4){0.f, 0.f, 0.f, 0.f};

    #pragma unroll
    for (int c = 0; c < NCHUNK; ++c) {
        short8 afrag = wpk[c * 64 + lane];

        int tap = c * 4 + quad;
        int k1 = tap / 27; int rem = tap - k1 * 27;
        int k2 = rem / 9;  rem -= k2 * 9;
        int k3 = rem / 3;
        int k4 = rem - k3 * 3;
        int q1 = p1 + k1 - 1, q2 = p2 + k2 - 1, q3 = p3 + k3 - 1, q4 = p4 + k4 - 1;
        bool valid = ((unsigned)q1 < (unsigned)SDIM) & ((unsigned)q2 < (unsigned)SDIM) &
                     ((unsigned)q3 < (unsigned)SDIM) & ((unsigned)q4 < (unsigned)SDIM);
        int q = ((q1 * SDIM + q2) * SDIM + q3) * SDIM + q4;

        short8 bf[NB];
        #pragma unroll
        for (int t = 0; t < NB; ++t) {
            const short8* src = valid ? (xb[t] + q) : zslt;
            bf[t] = *src;
        }
        #pragma unroll
        for (int t = 0; t < NB; ++t)
            acc[t] = __builtin_amdgcn_mfma_f32_16x16x32_bf16(afrag, bf[t], acc[t], 0, 0, 0);
    }

    f32x4 b4 = *(const f32x4*)(bias + quad * 4);
    #pragma unroll
    for (int t = 0; t < NB; ++t) {
        float* obase = out + ((size_t)(g * NB + t) * COUT + quad * 4) * SP + p;
        #pragma unroll
        for (int reg = 0; reg < 4; ++reg)
            obase[(size_t)reg * SP] = acc[t][reg] + b4[reg];
    }
}

// ---------- fallback (direct fp32) if ws too small ----------
__global__ __launch_bounds__(256) void conv4d_direct(
    const float* __restrict__ x, const float* __restrict__ w,
    const float* __restrict__ bias, float* __restrict__ out)
{
    int t = blockIdx.x * blockDim.x + threadIdx.x;
    int b = t / SP;
    int p = t - b * SP;
    int p4 = p % SDIM; int tmp = p / SDIM;
    int p3 = tmp % SDIM; tmp /= SDIM;
    int p2 = tmp % SDIM; int p1 = tmp / SDIM;
    float acc[COUT];
    #pragma unroll
    for (int o = 0; o < COUT; ++o) acc[o] = bias[o];
    const float* xb = x + (size_t)b * CIN * SP;
    for (int k1 = 0; k1 < 3; ++k1) {
        unsigned q1 = (unsigned)(p1 + k1 - 1); if (q1 >= SDIM) continue;
        for (int k2 = 0; k2 < 3; ++k2) {
            unsigned q2 = (unsigned)(p2 + k2 - 1); if (q2 >= SDIM) continue;
            for (int k3 = 0; k3 < 3; ++k3) {
                unsigned q3 = (unsigned)(p3 + k3 - 1); if (q3 >= SDIM) continue;
                int base123 = (((int)q1 * SDIM + (int)q2) * SDIM + (int)q3) * SDIM;
                int kf = ((k1 * 3 + k2) * 3 + k3) * 3;
                for (int k4 = 0; k4 < 3; ++k4) {
                    unsigned q4 = (unsigned)(p4 + k4 - 1); if (q4 >= SDIM) continue;
                    int q = base123 + (int)q4;
                    float xv[CIN];
                    #pragma unroll
                    for (int c = 0; c < CIN; ++c) xv[c] = xb[c * SP + q];
                    const float* wp = w + (kf + k4) * CIN;
                    #pragma unroll
                    for (int o = 0; o < COUT; ++o)
                        #pragma unroll
                        for (int c = 0; c < CIN; ++c)
                            acc[o] = fmaf(xv[c], wp[o * KW + c], acc[o]);
                }
            }
        }
    }
    float* ob = out + (size_t)b * COUT * SP + p;
    #pragma unroll
    for (int o = 0; o < COUT; ++o) ob[o * SP] = acc[o];
}

extern "C" void kernel_launch(void* const* d_in, const int* in_sizes, int n_in,
                              void* d_out, int out_size, void* d_ws, size_t ws_size,
                              hipStream_t stream)
{
    const float* x    = (const float*)d_in[0];
    const float* w    = (const float*)d_in[1];
    const float* bias = (const float*)d_in[2];
    float* out        = (float*)d_out;
    unsigned char* ws = (unsigned char*)d_ws;

    if (ws_size >= WS_NEEDED_PAD) {
        // LDS-staged fast path
        hipLaunchKernelGGL(prep_fused, dim3(PREP_BLOCKS), dim3(256), 0, stream,
                           x, w, ws);
        hipLaunchKernelGGL(conv4d_lds, dim3(NBLK), dim3(256), 0, stream,
                           (const unsigned char*)ws, bias, out);
        return;
    }

    if (ws_size >= WS_NEEDED_OLD) {
        // old unpadded path
        hipLaunchKernelGGL(pack_weights, dim3(6), dim3(256), 0, stream, w, ws);
        const int pair_total = BATCH * SP / 2;
        hipLaunchKernelGGL(transpose_x, dim3(pair_total / 256), dim3(256), 0, stream, x, ws);
        hipLaunchKernelGGL(conv4d_mfma, dim3(NBLOCKS_OLD), dim3(256), 0, stream,
                           (const unsigned char*)ws, bias, out);
        return;
    }

    // insurance
    const int total = BATCH * SP;
    hipLaunchKernelGGL(conv4d_direct, dim3(total / 256), dim3(256), 0, stream,
                       x, w, bias, out);
}

// Round 7
// 387.532 us; speedup vs baseline: 1.1693x; 1.1693x over previous
//
#include <hip/hip_runtime.h>
#include <hip/hip_bf16.h>

// 4-D "same" conv as implicit GEMM on bf16 MFMA.
// R7: LDS-staged B v2. R6 post-mortem: mechanism right, implementation had
//   (1) 14.3M bank conflicts (row stride 10 slots -> (40c3+4c4)%32 collisions)
//   (2) 22% occupancy (2 blocks/CU) -> latency unhidden. Fixes:
//   - r4-stride padded to 12 slots: quad bank starts (16c3+4c4)%32 = uniform
//     2-way (free); tap deltas shift by multiples of 4 banks (stays uniform).
//   - NB=2 batches staged (34.5 KB LDS) + weights from GLOBAL (L1-broadcast)
//     -> 4 blocks/CU, DS pipe freed of A-frag reads.
//   - voffs[21] in registers (once/wave) kills per-chunk ds_read_b32.
//   DS floor: 3.48M ds_read_b128 x 12cyc / 256CU ~ 68 us.
// Paths: LDS-MFMA (ws >= 58.5 MB) -> old unpadded-MFMA (ws >= 42.5 MB)
//        -> direct fp32 (insurance).

#define SDIM  24
#define SP    (SDIM * SDIM * SDIM * SDIM)   // 331776
#define PD    26
#define SPPAD (PD * PD * PD * PD)            // 456976
#define CIN   8
#define COUT  16
#define BATCH 8
#define KW    648                            // 81 * CIN
#define NCHUNK 21                            // ceil(648/32)
#define PTILES (SP / 16)                     // 20736 (fallback path)
#define NBLOCKS_OLD (2 * PTILES / 4)

// new-block grid: 4 batch-pairs x 24 p1 x 24 p2 x 3 S3 x 3 S4
#define NBLK2 (4 * 24 * 24 * 3 * 3)          // 20736

#define ZERO_OFF 0
#define WPK_OFF  256
#define XT_OFF   32768
#define XT_BYTES  ((size_t)BATCH * SP * CIN * 2)          // 42,467,328
#define XTP_BYTES ((size_t)BATCH * SPPAD * CIN * 2)       // 58,492,928
#define WS_NEEDED_OLD (XT_OFF + XT_BYTES)
#define WS_NEEDED_PAD (XT_OFF + XTP_BYTES)

// ---- halo shell enumeration (per batch): SPPAD - SP = 125,200 slots ----
#define HALO_PER_B   125200
#define HROW_SLOTS   97552
#define HALO_TOTAL   (BATCH * HALO_PER_B)    // 1,001,600
#define HBLOCKS      3913                    // ceil(HALO_TOTAL/256)
#define TBLOCKS      (BATCH * SP / 4 / 256)  // 2592 transpose blocks
#define WBLOCKS      6                       // weight-pack blocks
#define PREP_BLOCKS  (HBLOCKS + TBLOCKS + WBLOCKS)

typedef __attribute__((ext_vector_type(8))) short short8;   // 8 bf16 = 4 VGPRs
typedef __attribute__((ext_vector_type(4))) float f32x4;

static __device__ __forceinline__ unsigned short f2bf(float f) {
    unsigned u = __builtin_bit_cast(unsigned, f);
    u = (u + 0x7fffu + ((u >> 16) & 1u)) >> 16;          // RNE
    return (unsigned short)u;
}

// ---------- fused prepass: halo-zero + transpose + weights (unchanged) ----------
__global__ __launch_bounds__(256) void prep_fused(
    const float* __restrict__ x, const float* __restrict__ w,
    unsigned char* __restrict__ ws)
{
    const int bid = blockIdx.x;
    const int tid = threadIdx.x;

    if (bid < HBLOCKS) {
        // ---- halo-only zero fill ----
        int t = bid * 256 + tid;
        if (t >= HALO_TOTAL) return;
        int b = t / HALO_PER_B;
        int h = t - b * HALO_PER_B;
        int q1, q2, q3, q4;
        if (h < HROW_SLOTS) {
            int rid = h / 26;
            q4 = h - rid * 26;
            if (rid < 1352) {                            // q1 in {0,25}
                q1 = (rid < 676) ? 0 : 25;
                int rr = rid % 676;
                q2 = rr / 26; q3 = rr - (rr / 26) * 26;
            } else if (rid < 2600) {                     // q1 in [1,24], q2 in {0,25}
                int r2 = rid - 1352;
                q1 = 1 + r2 / 52;
                int rr = r2 - (r2 / 52) * 52;
                q2 = (rr < 26) ? 0 : 25;
                q3 = rr % 26;
            } else {                                     // q1,q2 in [1,24], q3 in {0,25}
                int r3 = rid - 2600;
                q1 = 1 + r3 / 48;
                int rr = r3 - (r3 / 48) * 48;
                q2 = 1 + rr / 2;
                q3 = (rr & 1) ? 25 : 0;
            }
        } else {
            int e = h - HROW_SLOTS;                      // [0, 27648)
            int rid = e >> 1;
            q4 = (e & 1) ? 25 : 0;
            q1 = 1 + rid / 576;
            int rr = rid - (rid / 576) * 576;
            q2 = 1 + rr / 24;
            q3 = 1 + rr - (rr / 24) * 24;
        }
        size_t slot = (size_t)b * SPPAD + (((q1 * PD + q2) * PD + q3) * PD + q4);
        short8 z = {0, 0, 0, 0, 0, 0, 0, 0};
        ((short8*)(ws + XT_OFF))[slot] = z;
        return;
    }

    if (bid < HBLOCKS + TBLOCKS) {
        // ---- transpose: x (B,CIN,SP) fp32 -> xTp interior (B,26^4,CIN) bf16 ----
        int idx = (bid - HBLOCKS) * 256 + tid;
        int b  = idx / (SP / 4);
        int pq = idx - b * (SP / 4);
        int p  = pq * 4;
        const float* xb = x + (size_t)b * CIN * SP + p;

        float4 v[CIN];
        #pragma unroll
        for (int c = 0; c < CIN; ++c)
            v[c] = *(const float4*)(xb + (size_t)c * SP);

        union { __hip_bfloat162 h2[4]; short8 s8; } u[4];
        #pragma unroll
        for (int j = 0; j < 4; ++j) {
            #pragma unroll
            for (int i = 0; i < 4; ++i) {
                float a0 = (&v[2 * i].x)[j];
                float a1 = (&v[2 * i + 1].x)[j];
                u[j].h2[i] = __float22bfloat162_rn(make_float2(a0, a1));
            }
        }

        int r = p;
        const int p4 = r % SDIM; r /= SDIM;
        const int p3 = r % SDIM; r /= SDIM;
        const int p2 = r % SDIM;
        const int p1 = r / SDIM;
        int qp = (((p1 + 1) * PD + (p2 + 1)) * PD + (p3 + 1)) * PD + (p4 + 1);

        short8* dst = (short8*)(ws + XT_OFF) + (size_t)b * SPPAD + qp;
        #pragma unroll
        for (int j = 0; j < 4; ++j) dst[j] = u[j].s8;
        return;
    }

    // ---- weight pack -> A-frag order Wpack[chunk][lane][8] bf16 ----
    int t = (bid - HBLOCKS - TBLOCKS) * 256 + tid;
    if (t >= NCHUNK * 64) return;
    int chunk = t >> 6;
    int lane  = t & 63;
    int m     = lane & 15;
    int quad  = lane >> 4;
    short8 pk;
    #pragma unroll
    for (int j = 0; j < 8; ++j) {
        int k = chunk * 32 + quad * 8 + j;
        float f = (k < KW) ? w[m * KW + k] : 0.0f;
        pk[j] = (short)f2bf(f);
    }
    ((short8*)(ws + WPK_OFF))[chunk * 64 + lane] = pk;
}

// ---------- main: LDS-staged implicit GEMM v2 ----------
// block: (g=batch-pair, p1, p2, S3, S4); stage x region (3,3,10,10)xCIN for
// 2 batches at r4-stride 12 (bank-uniform). Weights from global (L1-resident).
// wave (wt3,wt4) = one 4x4 (p3,p4) tile; lane col -> (c3,c4).
__global__ __launch_bounds__(256, 4) void conv4d_lds2(
    const unsigned char* __restrict__ ws,
    const float* __restrict__ bias,
    float* __restrict__ out)
{
    __shared__ short8 s_x[2][1080];           // 34,560 B [batch][((d1*3+d2)*10+r3)*12+r4]

    const int tid  = threadIdx.x;
    const int lane = tid & 63;
    const int wave = tid >> 6;
    const int col  = lane & 15;
    const int quad = lane >> 4;
    const int c3   = col >> 2;
    const int c4   = col & 3;
    const int wt3  = wave >> 1;
    const int wt4  = wave & 1;

    // block coords
    int bid = __builtin_amdgcn_readfirstlane((int)blockIdx.x);
    const int g  = bid / 5184;  int r = bid - g * 5184;   // batch pair 0..3
    const int p1 = r / 216;     r -= p1 * 216;
    const int p2 = r / 9;       int s = r - p2 * 9;
    const int S3 = (s / 3) * 8;
    const int S4 = (s % 3) * 8;

    // stage x region (1800 slots, strided r4-pad-12 layout)
    const short8* xT = (const short8*)(ws + XT_OFF);
    for (int t = tid; t < 1800; t += 256) {
        int b  = t / 900;
        int rr = t - b * 900;
        int d1 = rr / 300;  rr -= d1 * 300;
        int d2 = rr / 100;  rr -= d2 * 100;
        int r3 = rr / 10;
        int r4 = rr - r3 * 10;
        size_t gq = (((size_t)(p1 + d1) * PD + (p2 + d2)) * PD + (S3 + r3)) * PD + (S4 + r4);
        s_x[b][((d1 * 3 + d2) * 10 + r3) * 12 + r4] = xT[(size_t)(g * 2 + b) * SPPAD + gq];
    }

    // per-wave register voffs (no per-chunk LDS delta read)
    const int lane_off = (wt3 * 4 + c3) * 12 + (wt4 * 4 + c4);
    int voffs[NCHUNK];
    #pragma unroll
    for (int c = 0; c < NCHUNK; ++c) {
        int tap = c * 4 + quad;
        int dly = 0;
        if (tap < 81) {
            int k1 = tap / 27, rem = tap - k1 * 27;
            int k2 = rem / 9;  rem -= k2 * 9;
            int k3 = rem / 3;
            int k4 = rem - k3 * 3;
            dly = ((k1 * 3 + k2) * 10 + k3) * 12 + k4;
        }
        voffs[c] = dly + lane_off;
    }

    __syncthreads();

    const short8* wpk = (const short8*)(ws + WPK_OFF);

    f32x4 acc0 = (f32x4){0.f, 0.f, 0.f, 0.f};
    f32x4 acc1 = (f32x4){0.f, 0.f, 0.f, 0.f};

    #pragma unroll
    for (int c = 0; c < NCHUNK; ++c) {
        short8 afrag = wpk[c * 64 + lane];               // global, L1-broadcast
        short8 bf0 = s_x[0][voffs[c]];                   // ds_read_b128, 2-way free
        short8 bf1 = s_x[1][voffs[c]];
        acc0 = __builtin_amdgcn_mfma_f32_16x16x32_bf16(afrag, bf0, acc0, 0, 0, 0);
        acc1 = __builtin_amdgcn_mfma_f32_16x16x32_bf16(afrag, bf1, acc1, 0, 0, 0);
    }

    // epilogue: D[row=quad*4+reg][col] -> out[b][row][p1,p2,p3,p4] ; add bias
    const int p3 = S3 + wt3 * 4 + c3;
    const int p4 = S4 + wt4 * 4 + c4;
    const size_t pos = (((size_t)p1 * SDIM + p2) * SDIM + p3) * SDIM + p4;
    f32x4 b4 = *(const f32x4*)(bias + quad * 4);
    {
        float* obase = out + ((size_t)(g * 2 + 0) * COUT + quad * 4) * SP + pos;
        #pragma unroll
        for (int reg = 0; reg < 4; ++reg)
            obase[(size_t)reg * SP] = acc0[reg] + b4[reg];
    }
    {
        float* obase = out + ((size_t)(g * 2 + 1) * COUT + quad * 4) * SP + pos;
        #pragma unroll
        for (int reg = 0; reg < 4; ++reg)
            obase[(size_t)reg * SP] = acc1[reg] + b4[reg];
    }
}

// ================= old (unpadded) path — middle fallback =================

__global__ __launch_bounds__(256) void pack_weights(
    const float* __restrict__ w, unsigned char* __restrict__ ws)
{
    int t = blockIdx.x * 256 + threadIdx.x;
    if (t == 1344) {
        short8 z = {0,0,0,0,0,0,0,0};
        *(short8*)(ws + ZERO_OFF) = z;
    }
    if (t >= NCHUNK * 64) return;
    int chunk = t >> 6;
    int lane  = t & 63;
    int m     = lane & 15;
    int quad  = lane >> 4;
    short8 pk;
    #pragma unroll
    for (int j = 0; j < 8; ++j) {
        int k = chunk * 32 + quad * 8 + j;
        float f = (k < KW) ? w[m * KW + k] : 0.0f;
        pk[j] = (short)f2bf(f);
    }
    ((short8*)(ws + WPK_OFF))[chunk * 64 + lane] = pk;
}

__global__ __launch_bounds__(256) void transpose_x(
    const float* __restrict__ x, unsigned char* __restrict__ ws)
{
    int idx = blockIdx.x * 256 + threadIdx.x;
    int b  = idx / (SP / 2);
    int pp = idx - b * (SP / 2);
    int p  = pp * 2;
    const float* xb = x + (size_t)b * CIN * SP + p;

    float2 v[CIN];
    #pragma unroll
    for (int c = 0; c < CIN; ++c)
        v[c] = *(const float2*)(xb + (size_t)c * SP);

    union { __hip_bfloat162 h2[4]; short8 s8; } u0, u1;
    #pragma unroll
    for (int i = 0; i < 4; ++i) {
        float2 a = make_float2(v[2 * i].x, v[2 * i + 1].x);
        float2 bq = make_float2(v[2 * i].y, v[2 * i + 1].y);
        u0.h2[i] = __float22bfloat162_rn(a);
        u1.h2[i] = __float22bfloat162_rn(bq);
    }
    short8* dst = (short8*)(ws + XT_OFF) + ((size_t)b * SP + p);
    dst[0] = u0.s8;
    dst[1] = u1.s8;
}

__global__ __launch_bounds__(256) void conv4d_mfma(
    const unsigned char* __restrict__ ws,
    const float* __restrict__ bias,
    float* __restrict__ out)
{
    const int lane = threadIdx.x & 63;
    const int wave = threadIdx.x >> 6;
    const int col  = lane & 15;
    const int quad = lane >> 4;

    int W = blockIdx.x * 4 + wave;
    W = __builtin_amdgcn_readfirstlane(W);
    const int pt = W % PTILES;
    const int g  = W / PTILES;

    const int p = pt * 16 + col;
    int r = p;
    const int p4 = r % SDIM; r /= SDIM;
    const int p3 = r % SDIM; r /= SDIM;
    const int p2 = r % SDIM;
    const int p1 = r / SDIM;

    const short8* wpk  = (const short8*)(ws + WPK_OFF);
    const short8* xT   = (const short8*)(ws + XT_OFF);
    const short8* zslt = (const short8*)(ws + ZERO_OFF);

    const short8* xb[4];
    #pragma unroll
    for (int t = 0; t < 4; ++t)
        xb[t] = xT + (size_t)(g * 4 + t) * SP;

    f32x4 acc[4];
    #pragma unroll
    for (int t = 0; t < 4; ++t) acc[t] = (f32x4){0.f, 0.f, 0.f, 0.f};

    #pragma unroll
    for (int c = 0; c < NCHUNK; ++c) {
        short8 afrag = wpk[c * 64 + lane];

        int tap = c * 4 + quad;
        int k1 = tap / 27; int rem = tap - k1 * 27;
        int k2 = rem / 9;  rem -= k2 * 9;
        int k3 = rem / 3;
        int k4 = rem - k3 * 3;
        int q1 = p1 + k1 - 1, q2 = p2 + k2 - 1, q3 = p3 + k3 - 1, q4 = p4 + k4 - 1;
        bool valid = ((unsigned)q1 < (unsigned)SDIM) & ((unsigned)q2 < (unsigned)SDIM) &
                     ((unsigned)q3 < (unsigned)SDIM) & ((unsigned)q4 < (unsigned)SDIM);
        int q = ((q1 * SDIM + q2) * SDIM + q3) * SDIM + q4;

        short8 bf[4];
        #pragma unroll
        for (int t = 0; t < 4; ++t) {
            const short8* src = valid ? (xb[t] + q) : zslt;
            bf[t] = *src;
        }
        #pragma unroll
        for (int t = 0; t < 4; ++t)
            acc[t] = __builtin_amdgcn_mfma_f32_16x16x32_bf16(afrag, bf[t], acc[t], 0, 0, 0);
    }

    f32x4 b4 = *(const f32x4*)(bias + quad * 4);
    #pragma unroll
    for (int t = 0; t < 4; ++t) {
        float* obase = out + ((size_t)(g * 4 + t) * COUT + quad * 4) * SP + p;
        #pragma unroll
        for (int reg = 0; reg < 4; ++reg)
            obase[(size_t)reg * SP] = acc[t][reg] + b4[reg];
    }
}

// ---------- fallback (direct fp32) if ws too small ----------
__global__ __launch_bounds__(256) void conv4d_direct(
    const float* __restrict__ x, const float* __restrict__ w,
    const float* __restrict__ bias, float* __restrict__ out)
{
    int t = blockIdx.x * blockDim.x + threadIdx.x;
    int b = t / SP;
    int p = t - b * SP;
    int p4 = p % SDIM; int tmp = p / SDIM;
    int p3 = tmp % SDIM; tmp /= SDIM;
    int p2 = tmp % SDIM; int p1 = tmp / SDIM;
    float acc[COUT];
    #pragma unroll
    for (int o = 0; o < COUT; ++o) acc[o] = bias[o];
    const float* xb = x + (size_t)b * CIN * SP;
    for (int k1 = 0; k1 < 3; ++k1) {
        unsigned q1 = (unsigned)(p1 + k1 - 1); if (q1 >= SDIM) continue;
        for (int k2 = 0; k2 < 3; ++k2) {
            unsigned q2 = (unsigned)(p2 + k2 - 1); if (q2 >= SDIM) continue;
            for (int k3 = 0; k3 < 3; ++k3) {
                unsigned q3 = (unsigned)(p3 + k3 - 1); if (q3 >= SDIM) continue;
                int base123 = (((int)q1 * SDIM + (int)q2) * SDIM + (int)q3) * SDIM;
                int kf = ((k1 * 3 + k2) * 3 + k3) * 3;
                for (int k4 = 0; k4 < 3; ++k4) {
                    unsigned q4 = (unsigned)(p4 + k4 - 1); if (q4 >= SDIM) continue;
                    int q = base123 + (int)q4;
                    float xv[CIN];
                    #pragma unroll
                    for (int c = 0; c < CIN; ++c) xv[c] = xb[c * SP + q];
                    const float* wp = w + (kf + k4) * CIN;
                    #pragma unroll
                    for (int o = 0; o < COUT; ++o)
                        #pragma unroll
                        for (int c = 0; c < CIN; ++c)
                            acc[o] = fmaf(xv[c], wp[o * KW + c], acc[o]);
                }
            }
        }
    }
    float* ob = out + (size_t)b * COUT * SP + p;
    #pragma unroll
    for (int o = 0; o < COUT; ++o) ob[o * SP] = acc[o];
}

extern "C" void kernel_launch(void* const* d_in, const int* in_sizes, int n_in,
                              void* d_out, int out_size, void* d_ws, size_t ws_size,
                              hipStream_t stream)
{
    const float* x    = (const float*)d_in[0];
    const float* w    = (const float*)d_in[1];
    const float* bias = (const float*)d_in[2];
    float* out        = (float*)d_out;
    unsigned char* ws = (unsigned char*)d_ws;

    if (ws_size >= WS_NEEDED_PAD) {
        // LDS-staged fast path v2
        hipLaunchKernelGGL(prep_fused, dim3(PREP_BLOCKS), dim3(256), 0, stream,
                           x, w, ws);
        hipLaunchKernelGGL(conv4d_lds2, dim3(NBLK2), dim3(256), 0, stream,
                           (const unsigned char*)ws, bias, out);
        return;
    }

    if (ws_size >= WS_NEEDED_OLD) {
        // old unpadded path
        hipLaunchKernelGGL(pack_weights, dim3(6), dim3(256), 0, stream, w, ws);
        const int pair_total = BATCH * SP / 2;
        hipLaunchKernelGGL(transpose_x, dim3(pair_total / 256), dim3(256), 0, stream, x, ws);
        hipLaunchKernelGGL(conv4d_mfma, dim3(NBLOCKS_OLD), dim3(256), 0, stream,
                           (const unsigned char*)ws, bias, out);
        return;
    }

    // insurance
    const int total = BATCH * SP;
    hipLaunchKernelGGL(conv4d_direct, dim3(total / 256), dim3(256), 0, stream,
                       x, w, bias, out);
}